// Round 7
// baseline (199.699 us; speedup 1.0000x reference)
//
#include <hip/hip_runtime.h>
#include <math.h>

#define T_DIM 512
#define TP 8
#define NC 65            // 2*16*2 + 1 candidates
#define NJ 128
#define BLOCK 576        // 9 waves
#define LOG2E 1.4426950408889634f
#define LN2   0.6931471805599453f
#define CORR_L2 8.617045f   // log2(50257/128)

__device__ __forceinline__ float i2f(int x) { return __int_as_float(x); }
__device__ __forceinline__ int   f2i(float x) { return __float_as_int(x); }

__device__ __forceinline__ int cand_v(int c, int sta, const int* s_rand, int p) {
    if (c == 32) return sta;
    const int cc = (c < 32) ? c : (c - 33);
    const int h = cc >> 1;
    const int r = (sta ^ (1 << h)) ^ (s_rand[cc * TP + p] & ((1 << h) - 1));
    return (c < 32) ? r : -r;
}

// one cos term: d = csim/8 + B; acc += d*d*|eu|   (uniform DAG per candidate)
#define COS_STEP(va, vs, X, acc) do {                                   \
    const int _x = (va) ^ (X).x;                                        \
    const float _u8 = fmaf((float)__clz(_x + 1), 0.0078125f, -0.125f);  \
    const float _d = i2f(f2i(_u8) ^ ((vs) ^ (X).y)) + i2f((X).z);       \
    (acc) = fmaf(_d * _d, i2f((X).w), (acc));                           \
} while (0)

// one cro z-term (log2 domain): z = u*A + C
#define CRO_Z(va, vs, X) ({                                             \
    const int _x = (va) ^ (X).x;                                        \
    const float _u0 = fmaf((float)__clz(_x + 1), 0.0625f, -1.0f);       \
    const float _u = i2f(f2i(_u0) ^ ((vs) ^ (X).y));                    \
    fmaf(_u, i2f((X).w), i2f((X).z));                                   \
})

// ---------------- fused kernel: grid 512, block 576 ----------------
__global__ __launch_bounds__(BLOCK, 8) void cg_fused(
    const int* __restrict__ sta_loc,    // (T, 8)
    const int* __restrict__ nei_loc,    // (T, 128, 8)
    const int* __restrict__ voc_loc,    // (T, 128, 8)
    const float* __restrict__ sta_emb,  // (T, 256)
    const float* __restrict__ nei_emb,  // (T, 128, 256)
    const float* __restrict__ voc_emb,  // (T, 128, 256)
    const int* __restrict__ rand_masks, // (T, 32, 8)
    float* __restrict__ out)
{
    const int t = blockIdx.x;
    const int tid = threadIdx.x;

    __shared__ int4  s_pc4[2][NJ * TP];   // 32 KB: {qa, qsgn, B|C, ae|A}
    __shared__ float s_cspT[2][TP * 132]; // transposed csp, padded
    __shared__ float s_css[2][NJ];
    __shared__ float s_w[2][NJ];          // eu (side0) or A_k (side1)
    __shared__ float s_dot[NJ];           // nei only
    __shared__ float s_nn[2][NJ];
    __shared__ float s_lcos[NC * TP], s_lcro[NC * TP];
    __shared__ float s_Mpart[9 * 8];
    __shared__ float s_ss;
    __shared__ int   s_sta[TP];
    __shared__ int   s_rand[256];

    if (tid < 256) s_rand[tid] = rand_masks[t * 256 + tid];

    if (tid < 512) {
        // ---- P1 (waves 0-7): embedding sums, batched 12-deep loads ----
        const int g = tid >> 2, sub = tid & 3;
        const float4* sp = (const float4*)(sta_emb + (size_t)t * 256);
        const float4* np = (const float4*)(nei_emb + ((size_t)t * NJ + g) * 256);
        const float4* vp = (const float4*)(voc_emb + ((size_t)t * NJ + g) * 256);
        float dd = 0.f, nnn = 0.f, nnv = 0.f, ss = 0.f;
        #pragma unroll
        for (int q = 0; q < 4; ++q) {
            float4 a[4], b[4], c[4];
            #pragma unroll
            for (int i = 0; i < 4; ++i) {
                const int i4 = sub + 4 * (q * 4 + i);   // lanes 0-3 = one 64B line
                a[i] = sp[i4]; b[i] = np[i4]; c[i] = vp[i4];
            }
            #pragma unroll
            for (int i = 0; i < 4; ++i) {
                dd  += a[i].x * b[i].x + a[i].y * b[i].y + a[i].z * b[i].z + a[i].w * b[i].w;
                nnn += b[i].x * b[i].x + b[i].y * b[i].y + b[i].z * b[i].z + b[i].w * b[i].w;
                nnv += c[i].x * c[i].x + c[i].y * c[i].y + c[i].z * c[i].z + c[i].w * c[i].w;
                if (g == 0) ss += a[i].x * a[i].x + a[i].y * a[i].y + a[i].z * a[i].z + a[i].w * a[i].w;
            }
        }
        dd  += __shfl_xor(dd, 1);  dd  += __shfl_xor(dd, 2);
        nnn += __shfl_xor(nnn, 1); nnn += __shfl_xor(nnn, 2);
        nnv += __shfl_xor(nnv, 1); nnv += __shfl_xor(nnv, 2);
        if (g == 0) { ss += __shfl_xor(ss, 1); ss += __shfl_xor(ss, 2); }
        if (sub == 0) {
            s_dot[g] = dd; s_nn[0][g] = nnn; s_nn[1][g] = nnv;
            if (g == 0) s_ss = ss;
        }
    } else {
        // ---- P2 (wave 8, overlapped with P1): stage loc -> qa/qsgn + cspT ----
        const int l = tid - 512;                    // 0..63
        if (l < TP) s_sta[l] = sta_loc[t * TP + l];
        const int4 sta4 = ((const int4*)(sta_loc + t * TP))[l & 1];
        const int sarr[4] = {sta4.x, sta4.y, sta4.z, sta4.w};
        #pragma unroll
        for (int side = 0; side < 2; ++side) {
            const int* loc = side ? voc_loc : nei_loc;
            const int4* lp = (const int4*)(loc + (size_t)t * 1024);
            #pragma unroll
            for (int q = 0; q < 4; ++q) {
                const int4 pl4 = lp[q * 64 + l];
                const int j = q * 32 + (l >> 1);
                const int parr[4] = {pl4.x, pl4.y, pl4.z, pl4.w};
                #pragma unroll
                for (int e = 0; e < 4; ++e) {
                    const int pl = parr[e];
                    const int sta = sarr[e];
                    const int idx = q * 256 + 4 * l + e;
                    const int qa = pl < 0 ? -pl : pl;
                    const int qsgn = pl & 0x80000000;
                    const int sa = sta < 0 ? -sta : sta;
                    const int x = sa ^ qa;
                    const float u0 = fmaf((float)__clz(x + 1), 0.0625f, -1.0f);
                    const float csp = i2f(f2i(u0) ^ ((sta ^ pl) & 0x80000000));
                    ((int2*)&s_pc4[side][idx])[0] = make_int2(qa, qsgn);
                    s_cspT[side][(4 * (l & 1) + e) * 132 + j] = csp;
                }
            }
        }
    }
    __syncthreads();

    // ---- P3: css reduce + eu / A. 256 threads: j = tid>>1, side = tid&1 ----
    if (tid < 256) {
        const int j = tid >> 1, side = tid & 1;
        float cs = 0.f;
        #pragma unroll
        for (int p = 0; p < TP; ++p) cs += s_cspT[side][p * 132 + j];
        s_css[side][j] = cs;
        const float ns = sqrtf(s_ss);
        const float nn = s_nn[side][j];
        if (side == 0)
            s_w[0][j] = s_dot[j] / (fmaxf(sqrtf(nn), 1e-12f) * fmaxf(ns, 1e-12f));
        else
            s_w[1][j] = ns * sqrtf(nn) * (0.125f * LOG2E);   // A_k (>= 0)
    }
    __syncthreads();

    // ---- P4: repack {B|C, ae|A}; per-(wave,p) max of (C + A) for side1 ----
    {
        float mloc = -INFINITY;
        #pragma unroll
        for (int k = 0; k < 4; ++k) {
            const int item = tid + k * BLOCK;       // BLOCK%8==0: p invariant
            if (item < 2048) {
                const int side = item >> 10, idx = item & 1023;
                const int j = idx >> 3, p = idx & 7;
                const float csp = s_cspT[side][p * 132 + j];
                const float b = s_css[side][j] - csp;
                const float w = s_w[side][j];
                float z2, w2;
                if (side == 0) { z2 = fmaf(b, 0.125f, -w); w2 = fabsf(w); }
                else {
                    z2 = fmaf(b, w, j ? CORR_L2 : 0.0f);
                    w2 = w;
                    mloc = fmaxf(mloc, z2 + w);
                }
                ((int2*)&s_pc4[side][idx])[1] = make_int2(f2i(z2), f2i(w2));
            }
        }
        mloc = fmaxf(mloc, __shfl_xor(mloc, 8));
        mloc = fmaxf(mloc, __shfl_xor(mloc, 16));
        mloc = fmaxf(mloc, __shfl_xor(mloc, 32));
        const int lane = tid & 63;
        if (lane < 8) s_Mpart[(tid >> 6) * 8 + lane] = mloc;
    }
    __syncthreads();

    // ---- P5: 66 wave-tasks = (side, candidate-pair); lane-parallel over j ----
    // lane l: p = l&7, j = 8i + (l>>3), i = 0..15 -> flat f = i*64 + l
    // (stride-1 ds_read_b128, conflict-free). One uniform per-candidate FP DAG
    // (c = 64 runs the pair code with A = B) -> exact ties preserved.
    {
        const int wv = tid >> 6, l = tid & 63;
        const int p = l & 7;
        const int sta = s_sta[p];
        float M = s_Mpart[p];
        #pragma unroll
        for (int w8 = 1; w8 < 9; ++w8) M = fmaxf(M, s_Mpart[w8 * 8 + p]);

        for (int tsk = wv; tsk < 66; tsk += 9) {
            const int side = tsk & 1;
            const int cp = tsk >> 1;                // 0..32
            const int cA = (cp == 32) ? 64 : 2 * cp;
            const int cB = (cp == 32) ? 64 : 2 * cp + 1;
            const int vA = cand_v(cA, sta, s_rand, p);
            const int vB = cand_v(cB, sta, s_rand, p);
            const int vaA = vA < 0 ? -vA : vA, vsA = vA & 0x80000000;
            const int vaB = vB < 0 ? -vB : vB, vsB = vB & 0x80000000;

            if (side == 0) {
                const int4* pcf = s_pc4[0];
                float aA = 0.f, aB = 0.f;
                #pragma unroll
                for (int q = 0; q < 4; ++q) {
                    const int4 x0 = pcf[q * 256 + l];
                    const int4 x1 = pcf[q * 256 + 64 + l];
                    const int4 x2 = pcf[q * 256 + 128 + l];
                    const int4 x3 = pcf[q * 256 + 192 + l];
                    COS_STEP(vaA, vsA, x0, aA); COS_STEP(vaB, vsB, x0, aB);
                    COS_STEP(vaA, vsA, x1, aA); COS_STEP(vaB, vsB, x1, aB);
                    COS_STEP(vaA, vsA, x2, aA); COS_STEP(vaB, vsB, x2, aB);
                    COS_STEP(vaA, vsA, x3, aA); COS_STEP(vaB, vsB, x3, aB);
                }
                aA += __shfl_xor(aA, 8);  aB += __shfl_xor(aB, 8);
                aA += __shfl_xor(aA, 16); aB += __shfl_xor(aB, 16);
                aA += __shfl_xor(aA, 32); aB += __shfl_xor(aB, 32);
                if (l < 8) {
                    s_lcos[cA * TP + p] = aA * 0.0078125f;
                    s_lcos[cB * TP + p] = aB * 0.0078125f;
                }
            } else {
                const int4* pcf = s_pc4[1];
                float sA = 0.f, sB = 0.f, z0A = 0.f, z0B = 0.f;
                #pragma unroll
                for (int q = 0; q < 4; ++q) {
                    const int4 x0 = pcf[q * 256 + l];
                    const int4 x1 = pcf[q * 256 + 64 + l];
                    const int4 x2 = pcf[q * 256 + 128 + l];
                    const int4 x3 = pcf[q * 256 + 192 + l];
                    {
                        const float zA = CRO_Z(vaA, vsA, x0) - M;
                        const float zB = CRO_Z(vaB, vsB, x0) - M;
                        if (q == 0) { z0A = zA; z0B = zB; }   // j = 0 lives at i=0, lanes 0-7
                        sA += __builtin_amdgcn_exp2f(zA);
                        sB += __builtin_amdgcn_exp2f(zB);
                    }
                    sA += __builtin_amdgcn_exp2f(CRO_Z(vaA, vsA, x1) - M);
                    sB += __builtin_amdgcn_exp2f(CRO_Z(vaB, vsB, x1) - M);
                    sA += __builtin_amdgcn_exp2f(CRO_Z(vaA, vsA, x2) - M);
                    sB += __builtin_amdgcn_exp2f(CRO_Z(vaB, vsB, x2) - M);
                    sA += __builtin_amdgcn_exp2f(CRO_Z(vaA, vsA, x3) - M);
                    sB += __builtin_amdgcn_exp2f(CRO_Z(vaB, vsB, x3) - M);
                }
                sA += __shfl_xor(sA, 8);  sB += __shfl_xor(sB, 8);
                sA += __shfl_xor(sA, 16); sB += __shfl_xor(sB, 16);
                sA += __shfl_xor(sA, 32); sB += __shfl_xor(sB, 32);
                if (l < 8) {
                    s_lcro[cA * TP + p] =
                        (__builtin_amdgcn_logf(fmaxf(sA, 1e-38f)) - z0A) * LN2;
                    s_lcro[cB * TP + p] =
                        (__builtin_amdgcn_logf(fmaxf(sB, 1e-38f)) - z0B) * LN2;
                }
            }
        }
    }
    __syncthreads();

    // ---- P6: argmin (first-min) + gather + means, in-block ----
    float vc = 0.f, vr = 0.f, vt = 0.f;
    if (tid < TP) {
        const int p = tid;
        float best = INFINITY, blc = 0.f, blr = 0.f;
        int bc = 0;
        for (int c = 0; c < NC; ++c) {
            const float lc = s_lcos[c * TP + p];
            const float lr = s_lcro[c * TP + p];
            const float lt = fmaf(0.1f, lr, lc);
            if (lt < best) { best = lt; bc = c; blc = lc; blr = lr; }
        }
        out[t * TP + p] = (float)cand_v(bc, s_sta[p], s_rand, p);
        vc = blc; vr = blr; vt = best;
    }
    if (tid < 64) {
        vc += __shfl_xor(vc, 1); vc += __shfl_xor(vc, 2); vc += __shfl_xor(vc, 4);
        vr += __shfl_xor(vr, 1); vr += __shfl_xor(vr, 2); vr += __shfl_xor(vr, 4);
        vt += __shfl_xor(vt, 1); vt += __shfl_xor(vt, 2); vt += __shfl_xor(vt, 4);
        if (tid == 0) {
            out[T_DIM * TP + t] = vc * 0.125f;
            out[T_DIM * TP + T_DIM + t] = vr * 0.125f;
            out[T_DIM * TP + 2 * T_DIM + t] = vt * 0.125f;
        }
    }
}

extern "C" void kernel_launch(void* const* d_in, const int* in_sizes, int n_in,
                              void* d_out, int out_size, void* d_ws, size_t ws_size,
                              hipStream_t stream) {
    const int* sta_loc = (const int*)d_in[0];
    const int* nei_loc = (const int*)d_in[1];
    const int* voc_loc = (const int*)d_in[2];
    const float* sta_emb = (const float*)d_in[3];
    const float* nei_emb = (const float*)d_in[4];
    const float* voc_emb = (const float*)d_in[5];
    const int* rand_masks = (const int*)d_in[6];
    float* out = (float*)d_out;

    cg_fused<<<T_DIM, BLOCK, 0, stream>>>(
        sta_loc, nei_loc, voc_loc, sta_emb, nei_emb, voc_emb, rand_masks, out);
}